// Round 12
// baseline (13671.475 us; speedup 1.0000x reference)
//
#include <hip/hip_runtime.h>
#include <hip/hip_bf16.h>

// LSTM: B=64, S=512, H=768, L=2. Persistent scan per layer, 12 waves/WG
// (round-8/11 skeleton).
//   waves 0-5 (x): input projection, 1 step ahead, LDS ring (split8 on the
//                  fly -- off critical path, overlapped with poll).
//   waves 6-11 (h): recurrent projection; wave 6 polls; half1 waves finalize.
// ROUND 12: h-phase weights (Whh) PRE-SPLIT into per-wave fragment layout
// (prep kernel) -> per-step h weight access = 24 clean uint4 L2-hit loads,
// ZERO VALU. Rounds 8-11 proved the allocator will never keep the 96-VGPR
// fragment set resident (VGPR_Count pinned at 84 with remat+re-split every
// step); this makes the reload cheap instead of fighting the allocator.
// ws_size runtime branch: full L1 h-stream if ws fits, else 2-slot ring with
// bypass reads (both correctness-safe).

#define HID 768
#define FH  3072
#define SEQ 512
#define BAT 64
#define GB  16           // batches per group
#define WPG 64           // workgroups per group
#define CPW 12           // h-columns per workgroup (3 tiles x 4 cols)
#define NWG 256
#define TPB 768          // 12 waves
#define WBLK (12*64*8)   // u32 per (wid,lane6) weight block = 6144

typedef __attribute__((ext_vector_type(8))) __bf16 bf16x8;
typedef __attribute__((ext_vector_type(4))) float f32x4;
typedef unsigned int u32;
typedef unsigned long long u64;

__device__ __forceinline__ float sigm(float z) { return 1.f / (1.f + __expf(-z)); }
__device__ __forceinline__ float tanh_fast(float x) {
  float a = fabsf(x);
  float e = __expf(-2.f * a);
  float t = (1.f - e) / (1.f + e);
  return copysignf(t, x);
}
__device__ __forceinline__ unsigned short bfbits(__bf16 b) {
  union { __bf16 b; unsigned short s; } u; u.b = b; return u.s;
}
__device__ __forceinline__ __bf16 bits2bf(unsigned short s) {
  union { unsigned short s; __bf16 b; } u; u.s = s; return u.b;
}
__device__ __forceinline__ u32 packsplit(float v) {
  __bf16 h = (__bf16)v;
  __bf16 l = (__bf16)(v - (float)h);
  return ((u32)bfbits(h) << 16) | (u32)bfbits(l);
}
__device__ __forceinline__ void split8(const float* p, bf16x8& hi, bf16x8& lo) {
  const float4* q = (const float4*)p;
  float4 a = q[0], b = q[1];
  float v[8] = {a.x, a.y, a.z, a.w, b.x, b.y, b.z, b.w};
#pragma unroll
  for (int i = 0; i < 8; ++i) {
    __bf16 h = (__bf16)v[i];
    hi[i] = h;
    lo[i] = (__bf16)(v[i] - (float)h);
  }
}
__device__ __forceinline__ void unpack8(const u32 w[8], bf16x8& hi, bf16x8& lo) {
#pragma unroll
  for (int i = 0; i < 8; ++i) {
    hi[i] = bits2bf((unsigned short)(w[i] >> 16));
    lo[i] = bits2bf((unsigned short)(w[i] & 0xffffu));
  }
}
__device__ __forceinline__ bf16x8 q2b(uint4 q) {
  union { uint4 q; bf16x8 v; } u; u.q = q; return u.v;
}
__device__ __forceinline__ uint4 b2q(bf16x8 v) {
  union { bf16x8 v; uint4 q; } u; u.v = v; return u.q;
}

// ---- prep: split Whh (both layers) into per-wave fragment layout ----
// t = (((layer*64 + wid)*6 + lane6)*12 + kk)*64 + lane, 32B per t (hi16,lo16)
__global__ void pack_wh(const float* __restrict__ Whh, u32* __restrict__ wpk) {
  const int NT = 2*64*6*12*64;     // 589,824
  int t = blockIdx.x * blockDim.x + threadIdx.x;
  if (t >= NT) return;
  int lane = t & 63; int r = t >> 6;
  int kk = r % 12;  r /= 12;
  int lane6 = r % 6; r /= 6;
  int wid = r % 64; r /= 64;
  int layer = r;                   // 0..1
  int tile = lane6 >> 1, half = lane6 & 1;
  int l15 = lane & 15, lhi = lane >> 4;
  int colA = wid*CPW + tile*4 + (l15 >> 2);
  int qA   = l15 & 3;
  int row  = qA*HID + colA;
  int k    = half*384 + kk*32 + lhi*8;
  const float* W = Whh + (size_t)layer*FH*HID;
  bf16x8 hi, lo;
  split8(W + (size_t)row*HID + k, hi, lo);
  u32* dst = wpk + (size_t)t * 8;
  *(uint4*)dst       = b2q(hi);
  *(uint4*)(dst + 4) = b2q(lo);
}

// K=384 x-projection slice (x-waves): weights split on the fly (off-path).
template<int FMT>
__device__ __forceinline__ f32x4 proj384(const float* xf, const u32* xp,
                                         size_t base,
                                         const bf16x8* ah, const bf16x8* al) {
  f32x4 acc[4];
#pragma unroll
  for (int r = 0; r < 4; ++r) acc[r] = f32x4{0.f, 0.f, 0.f, 0.f};
#pragma unroll
  for (int kk = 0; kk < 12; ++kk) {
    bf16x8 bhi, blo;
    if constexpr (FMT == 0) {
      split8(xf + base + kk*32, bhi, blo);
    } else {
      const uint4* p = (const uint4*)(xp + base + kk*32);
      uint4 A = p[0], B = p[1];
      u32 w[8] = {A.x, A.y, A.z, A.w, B.x, B.y, B.z, B.w};
      unpack8(w, bhi, blo);
    }
    acc[(3*kk+0)&3] = __builtin_amdgcn_mfma_f32_16x16x32_bf16(ah[kk], bhi, acc[(3*kk+0)&3], 0, 0, 0);
    acc[(3*kk+1)&3] = __builtin_amdgcn_mfma_f32_16x16x32_bf16(al[kk], bhi, acc[(3*kk+1)&3], 0, 0, 0);
    acc[(3*kk+2)&3] = __builtin_amdgcn_mfma_f32_16x16x32_bf16(ah[kk], blo, acc[(3*kk+2)&3], 0, 0, 0);
  }
  return acc[0] + acc[1] + acc[2] + acc[3];
}

template<int XFMT, int WRITE_OUT, int RING>
__attribute__((amdgpu_waves_per_eu(3, 3)))
__global__ void __launch_bounds__(TPB)
lstm_scan(const float* __restrict__ xf,   // XFMT==0: raw x [64][512][768] fp32
          const u32* __restrict__ xp,     // XFMT==1: packed pairs [512][64][768]
          const float* __restrict__ mask, // [64][512]
          const float* __restrict__ Wih,  // [3072][768] this layer (x-waves)
          const u32* __restrict__ whpk,   // pre-split Whh, this layer
          const float* __restrict__ bih,
          const float* __restrict__ bhh,
          u32* __restrict__ hdst,         // h store: RING? [2][64][768] : [512][64][768]
          const u32* __restrict__ hsrc,   // h read  (same buffer)
          float* __restrict__ out_f,      // WRITE_OUT: [64][512][768]
          float* __restrict__ hn,         // [64][768] this layer
          float* __restrict__ cn,
          int* __restrict__ flags)        // [NWG] this layer, zeroed
{
  __shared__ f32x4 xacc_l[24][3][64];     // 4-slot ring, padded to pin 1 blk/CU
  __shared__ f32x4 xpart_l[3][64];
  __shared__ f32x4 hpart_l[2][3][64];

  const int wg  = blockIdx.x;
  const int grp = wg >> 6;
  const int wid = wg & 63;
  const int tid = threadIdx.x;
  const int wv  = tid >> 6;        // 0..11
  const int l   = tid & 63;
  const int l15 = l & 15;
  const int lhi = l >> 4;

  const bool isx  = (wv < 6);
  const int lane6 = isx ? wv : (wv - 6);
  const int tile  = lane6 >> 1;    // 0..2
  const int half  = lane6 & 1;
  const int kofs  = half * 384;

  // x-wave weights (Wih): split-bf16 fragments (remat tolerated; off-path)
  const int colA = wid*CPW + tile*4 + (l15 >> 2);
  const int qA   = l15 & 3;
  bf16x8 ah[12], al[12];
  if (isx) {
    const float* wrow = Wih + (size_t)(qA*HID + colA)*HID + kofs + lhi*8;
#pragma unroll
    for (int kk = 0; kk < 12; ++kk) split8(wrow + kk*32, ah[kk], al[kk]);
  }
  // h-wave weights: pre-split fragment block base (clean uint4 loads per step)
  const u32* wbh = whpk + ((size_t)wid*6 + lane6) * WBLK;

  const int batch = grp*GB + l15;
  const int colO  = wid*CPW + tile*4 + lhi;
  float bias4[4] = {0.f, 0.f, 0.f, 0.f};
  if (!isx && half == 1) {
#pragma unroll
    for (int j = 0; j < 4; ++j) bias4[j] = bih[j*HID + colO] + bhh[j*HID + colO];
  }
  const float* mrow = mask + batch*SEQ;
  int* gflags = flags + grp*WPG;

  const int kb = kofs + lhi*8;

  float cstate = 0.f;

  // ---- prologue: xacc(0) ----
  {
    f32x4 px{0.f, 0.f, 0.f, 0.f};
    if (isx) {
      size_t base = (XFMT == 0) ? ((size_t)batch*SEQ)*HID + kb
                                : ((size_t)batch)*HID + kb;
      px = proj384<XFMT>(xf, xp, base, ah, al);
      if (half == 0) xpart_l[tile][l] = px;
    }
    __syncthreads();
    if (isx && half == 1) xacc_l[0][tile][l] = px + xpart_l[tile][l];
    __syncthreads();
  }

#pragma unroll 1
  for (int s = 0; s < SEQ; ++s) {
    // ---- phase0: x-waves compute s+1; wave 6 polls flag(s) ----
    f32x4 xa{0.f, 0.f, 0.f, 0.f};
    if (isx && s + 1 < SEQ) {
      size_t base = (XFMT == 0) ? ((size_t)batch*SEQ + (s+1))*HID + kb
                                : ((size_t)(s+1)*BAT + batch)*HID + kb;
      xa = proj384<XFMT>(xf, xp, base, ah, al);
      if (half == 0) xpart_l[tile][l] = xa;
    }
    if (!isx && lane6 == 0 && s > 0) {
      while (true) {
        int v = __hip_atomic_load(gflags + l, __ATOMIC_RELAXED, __HIP_MEMORY_SCOPE_AGENT);
        if (__all(v >= s)) break;
        __builtin_amdgcn_s_sleep(1);
      }
    }
    __syncthreads();   // b1

    // ---- phase1: h-waves: clean weight loads + h loads + MFMA ----
    f32x4 ha{0.f, 0.f, 0.f, 0.f};
    if (!isx && s > 0) {
      size_t base = RING ? ((size_t)((s-1) & 1)*BAT + batch)*HID + kb
                         : ((size_t)(s-1)*BAT + batch)*HID + kb;
      f32x4 acc[4];
#pragma unroll
      for (int r = 0; r < 4; ++r) acc[r] = f32x4{0.f, 0.f, 0.f, 0.f};
#pragma unroll
      for (int kk = 0; kk < 12; ++kk) {
        const uint4* wp = (const uint4*)(wbh + (size_t)(kk*64 + l)*8);
        bf16x8 Ah = q2b(wp[0]);
        bf16x8 Al = q2b(wp[1]);
        u32 w[8];
        if constexpr (RING) {
          const u64* sp = (const u64*)(hsrc + base + kk*32);
          u64 a = __hip_atomic_load(sp,     __ATOMIC_RELAXED, __HIP_MEMORY_SCOPE_AGENT);
          u64 b = __hip_atomic_load(sp + 1, __ATOMIC_RELAXED, __HIP_MEMORY_SCOPE_AGENT);
          u64 c = __hip_atomic_load(sp + 2, __ATOMIC_RELAXED, __HIP_MEMORY_SCOPE_AGENT);
          u64 d = __hip_atomic_load(sp + 3, __ATOMIC_RELAXED, __HIP_MEMORY_SCOPE_AGENT);
          w[0]=(u32)a; w[1]=(u32)(a>>32); w[2]=(u32)b; w[3]=(u32)(b>>32);
          w[4]=(u32)c; w[5]=(u32)(c>>32); w[6]=(u32)d; w[7]=(u32)(d>>32);
        } else {
          const uint4* p = (const uint4*)(hsrc + base + kk*32);
          uint4 A = p[0], B = p[1];
          w[0]=A.x; w[1]=A.y; w[2]=A.z; w[3]=A.w;
          w[4]=B.x; w[5]=B.y; w[6]=B.z; w[7]=B.w;
        }
        bf16x8 bhi, blo;
        unpack8(w, bhi, blo);
        acc[(3*kk+0)&3] = __builtin_amdgcn_mfma_f32_16x16x32_bf16(Ah, bhi, acc[(3*kk+0)&3], 0, 0, 0);
        acc[(3*kk+1)&3] = __builtin_amdgcn_mfma_f32_16x16x32_bf16(Al, bhi, acc[(3*kk+1)&3], 0, 0, 0);
        acc[(3*kk+2)&3] = __builtin_amdgcn_mfma_f32_16x16x32_bf16(Ah, blo, acc[(3*kk+2)&3], 0, 0, 0);
      }
      ha = acc[0] + acc[1] + acc[2] + acc[3];
      if (half == 0) hpart_l[s & 1][tile][l] = ha;
    }
    if (isx && half == 1 && s + 1 < SEQ)
      xacc_l[(s+1) & 3][tile][l] = xa + xpart_l[tile][l];
    __syncthreads();   // b2

    // ---- phase2: finalize (h half1 waves own the output) ----
    if (!isx && half == 1) {
      f32x4 z = xacc_l[s & 3][tile][l];
      if (s > 0) z = z + ha + hpart_l[s & 1][tile][l];
      float zi = z[0] + bias4[0], zf = z[1] + bias4[1];
      float zg = z[2] + bias4[2], zo = z[3] + bias4[3];
      float iv = sigm(zi), fv = sigm(zf), gv = tanh_fast(zg), ov = sigm(zo);
      float c  = fv*cstate + iv*gv;
      float hv = ov * tanh_fast(c);
      float m  = mrow[s];
      hv *= m; c *= m; cstate = c;

      u32 hw = packsplit(hv);
      size_t wrow = RING ? ((size_t)(s & 1)*BAT + batch)*HID + colO
                         : ((size_t)s*BAT + batch)*HID + colO;
      __hip_atomic_store(hdst + wrow, hw,
                         __ATOMIC_RELAXED, __HIP_MEMORY_SCOPE_AGENT);
      if constexpr (WRITE_OUT) {
        __builtin_nontemporal_store(hv, out_f + ((size_t)batch*SEQ + s)*HID + colO);
      }
      if (s == SEQ - 1) {
        hn[batch*HID + colO] = hv;
        cn[batch*HID + colO] = c;
      }
      asm volatile("s_waitcnt vmcnt(0)" ::: "memory");  // h at MALL before flag
    }
    __syncthreads();   // b3
    if (tid == 0)
      __hip_atomic_store(gflags + wid, s + 1,
                         __ATOMIC_RELAXED, __HIP_MEMORY_SCOPE_AGENT);
  }
}

extern "C" void kernel_launch(void* const* d_in, const int* in_sizes, int n_in,
                              void* d_out, int out_size, void* d_ws, size_t ws_size,
                              hipStream_t stream) {
  const float* x    = (const float*)d_in[0];
  const float* mask = (const float*)d_in[1];
  const float* Wih  = (const float*)d_in[2];
  const float* Whh  = (const float*)d_in[3];
  const float* bih  = (const float*)d_in[4];
  const float* bhh  = (const float*)d_in[5];
  float* out = (float*)d_out;

  char* ws = (char*)d_ws;
  const size_t WPKH_B  = (size_t)2*64*6*WBLK*4;                 // 18,874,368
  const size_t STREAM_B = (size_t)SEQ*BAT*HID*4;                // 100,663,296
  const size_t RING_B  = (size_t)2*BAT*HID*4;                   // 393,216

  u32* wpk = (u32*)ws;
  u32* opk = (u32*)(ws + WPKH_B);          // L0 h-stream = L1 input
  const bool big = ws_size >= WPKH_B + 2*STREAM_B + RING_B + 65536;
  u32* h1  = (u32*)(ws + WPKH_B + STREAM_B);      // L1 h store (stream or ring)
  int* flags = big ? (int*)(ws + WPKH_B + 2*STREAM_B)
                   : (int*)(ws + WPKH_B + STREAM_B + RING_B);

  (void)hipMemsetAsync(flags, 0, 2*NWG*sizeof(int), stream);
  pack_wh<<<2304, 256, 0, stream>>>(Whh, wpk);

  float* hn = out + 25165824;              // [2][64][768]
  float* cn = out + 25165824 + 98304;

  const size_t WLH = (size_t)64*6*WBLK;    // u32 per layer = 2,359,296

  // ---- layer 0: raw fp32 x, h-stream -> opk (plain-cached reads) ----
  lstm_scan<0, 0, 0><<<dim3(NWG), dim3(TPB), 0, stream>>>(
      x, nullptr, mask, Wih, wpk, bih, bhh,
      opk, opk, nullptr, hn, cn, flags);

  // ---- layer 1: opk input ----
  if (big) {
    lstm_scan<1, 1, 0><<<dim3(NWG), dim3(TPB), 0, stream>>>(
        nullptr, opk, mask, Wih + (size_t)FH*HID, wpk + WLH, bih + FH, bhh + FH,
        h1, h1, out, hn + 49152, cn + 49152, flags + NWG);
  } else {
    lstm_scan<1, 1, 1><<<dim3(NWG), dim3(TPB), 0, stream>>>(
        nullptr, opk, mask, Wih + (size_t)FH*HID, wpk + WLH, bih + FH, bhh + FH,
        h1, h1, out, hn + 49152, cn + 49152, flags + NWG);
  }
}